// Round 12
// baseline (200.305 us; speedup 1.0000x reference)
//
#include <hip/hip_runtime.h>
#include <hip/hip_bf16.h>
#include <stdint.h>

// Sizes (fixed by the problem)
#define B_SZ 2
#define S_LEN 2048
#define DM 1024
#define NH 16
#define DEPTH 64
#define M_ROWS (B_SZ * S_LEN)   // 4096
#define SCALE_Q 0.1803368801111144f   // log2(e)/sqrt(DEPTH), folded into Q proj

typedef __attribute__((ext_vector_type(8))) short bf16x8;    // 8 bf16 = 4 VGPRs
typedef __attribute__((ext_vector_type(4))) float f32x4;     // 16x16 C/D frag
typedef __attribute__((ext_vector_type(16))) float f32x16;   // 32x32 C/D frag

__device__ __forceinline__ unsigned short f2bf(float x) {
    union { float f; unsigned u; } a; a.f = x;
    unsigned r = a.u + 0x7FFF + ((a.u >> 16) & 1);   // RTNE
    return (unsigned short)(r >> 16);
}

__device__ __forceinline__ bf16x8 u4_to_bf8(uint4 u) {
    union { uint4 a; bf16x8 b; } c; c.a = u; return c.b;   // value bitcast
}

// v_cvt_pk_bf16_f32: D.lo = bf16(lo), D.hi = bf16(hi)  (RTNE). No builtin on
// gfx950 -> inline asm.
__device__ __forceinline__ unsigned cvtpk_bf16(float lo, float hi) {
    unsigned r;
    asm("v_cvt_pk_bf16_f32 %0, %1, %2" : "=v"(r) : "v"(lo), "v"(hi));
    return r;
}

// v_permlane32_swap_b32: a[hi lanes] <- b_old[lo lanes]; b[lo lanes] <-
// a_old[hi lanes]; a[lo], b[hi] unchanged.
__device__ __forceinline__ void permswap32(unsigned &a, unsigned &b) {
    auto r = __builtin_amdgcn_permlane32_swap(a, b, false, false);
    a = r[0]; b = r[1];
}

// async global->LDS, 16B per lane. LDS dest = wave-uniform base + lane*16.
__device__ __forceinline__ void async_ld16(const unsigned short* g, void* l) {
    __builtin_amdgcn_global_load_lds(
        (const __attribute__((address_space(1))) void*)g,
        (__attribute__((address_space(3))) void*)l,
        16, 0, 0);
}

// ===========================================================================
// FAST PATH
// ===========================================================================

// ---------------------------------------------------------------------------
// Kernel 1: fp32 -> bf16 convert (RTNE) of q,k,v,wq,wk,wv into ws.
// ---------------------------------------------------------------------------
__global__ __launch_bounds__(256)
void convert_kernel(const float* __restrict__ q, const float* __restrict__ k,
                    const float* __restrict__ v, const float* __restrict__ wq,
                    const float* __restrict__ wk, const float* __restrict__ wv,
                    unsigned short* __restrict__ dst) {
    const int z = blockIdx.y;
    const float* src = (z == 0) ? q : (z == 1) ? k : (z == 2) ? v
                     : (z == 3) ? wq : (z == 4) ? wk : wv;
    const size_t n4  = (z < 3) ? ((size_t)M_ROWS * DM / 4) : ((size_t)DM * DM / 4);
    const size_t off = (z < 3) ? ((size_t)z * M_ROWS * DM)
                               : ((size_t)3 * M_ROWS * DM + (size_t)(z - 3) * DM * DM);
    unsigned short* d = dst + off;
    const size_t stride = (size_t)gridDim.x * blockDim.x;
    for (size_t i = (size_t)blockIdx.x * blockDim.x + threadIdx.x; i < n4; i += stride) {
        float4 x = ((const float4*)src)[i];
        ushort4 p;
        p.x = f2bf(x.x); p.y = f2bf(x.y); p.z = f2bf(x.z); p.w = f2bf(x.w);
        ((ushort4*)d)[i] = p;
    }
}

// ---------------------------------------------------------------------------
// Kernel 2 (R17): bf16 NT GEMM, 128x128 tile, BK=64, global_load_lds,
// XOR-swizzled LDS, fused V-transpose epilogue (z==2 writes Vt directly).
// NEW: T1 XCD-aware chunked block swizzle — 96 consecutive virtual ids per
// XCD so B-panels (and partial A-panels) are fetched once per XCD instead
// of 8x.  Bijective remap: outputs bit-identical.
// ---------------------------------------------------------------------------
__global__ __launch_bounds__(256)
void proj_gemm3_kernel(const unsigned short* __restrict__ Xall,
                       const unsigned short* __restrict__ Wall,
                       unsigned short* __restrict__ Call,
                       unsigned short* __restrict__ Vtp) {
    __shared__ unsigned short SMEM[2 * 128 * 64];   // As | Bs; reused as scratch
    unsigned short* As = SMEM;
    unsigned short* Bs = SMEM + 128 * 64;

    // XCD-aware swizzle: nwg = 32*8*3 = 768 = 8 XCDs x 96.
    const int lin = blockIdx.x + (blockIdx.y << 5) + blockIdx.z * 256;
    const int v96 = (lin & 7) * 96 + (lin >> 3);   // bijective (768 % 8 == 0)
    const int xb  = v96 & 31;
    const int yb  = (v96 >> 5) & 7;
    const int z   = v96 >> 8;

    const unsigned short* X = Xall + (size_t)z * M_ROWS * DM;
    const unsigned short* W = Wall + (size_t)z * DM * DM;
    unsigned short* C = Call + (size_t)z * M_ROWS * DM;

    const int tid  = threadIdx.x;
    const int wave = tid >> 6;
    const int lane = tid & 63;
    const int l32  = lane & 31;
    const int s    = lane >> 5;
    const int m0 = xb * 128;
    const int n0 = yb * 128;
    const int wm = (wave >> 1) * 64;
    const int wn = (wave & 1) * 64;

    const int r8 = lane >> 3;
    const int sc = (lane & 7) ^ r8;

    f32x16 acc[2][2];
#pragma unroll
    for (int mi = 0; mi < 2; ++mi)
#pragma unroll
        for (int ni = 0; ni < 2; ++ni)
#pragma unroll
            for (int r = 0; r < 16; ++r) acc[mi][ni][r] = 0.f;

    for (int k0 = 0; k0 < DM; k0 += 64) {
#pragma unroll
        for (int i = 0; i < 4; ++i) {
            const int r = i * 32 + wave * 8 + r8;
            async_ld16(X + (size_t)(m0 + r) * DM + k0 + sc * 8,
                       (char*)As + i * 4096 + wave * 1024);
            async_ld16(W + (size_t)(n0 + r) * DM + k0 + sc * 8,
                       (char*)Bs + i * 4096 + wave * 1024);
        }
        __syncthreads();

#pragma unroll
        for (int ch = 0; ch < 4; ++ch) {
            bf16x8 af[2], bfr[2];
#pragma unroll
            for (int mi = 0; mi < 2; ++mi) {
                const int row = wm + mi * 32 + l32;
                af[mi] = *(const bf16x8*)&As[row * 64 + (((2 * ch + s) ^ (row & 7)) * 8)];
            }
#pragma unroll
            for (int ni = 0; ni < 2; ++ni) {
                const int row = wn + ni * 32 + l32;
                bfr[ni] = *(const bf16x8*)&Bs[row * 64 + (((2 * ch + s) ^ (row & 7)) * 8)];
            }
#pragma unroll
            for (int mi = 0; mi < 2; ++mi)
#pragma unroll
                for (int ni = 0; ni < 2; ++ni)
                    acc[mi][ni] = __builtin_amdgcn_mfma_f32_32x32x16_bf16(
                        af[mi], bfr[ni], acc[mi][ni], 0, 0, 0);
        }
        __syncthreads();
    }

    if (z < 2) {
        const float scale = (z == 0) ? SCALE_Q : 1.0f;
#pragma unroll
        for (int mi = 0; mi < 2; ++mi)
#pragma unroll
            for (int ni = 0; ni < 2; ++ni)
#pragma unroll
                for (int r = 0; r < 16; ++r) {
                    const int row = m0 + wm + mi * 32 + (r & 3) + 8 * (r >> 2) + 4 * s;
                    const int col = n0 + wn + ni * 32 + l32;
                    C[(size_t)row * DM + col] = f2bf(acc[mi][ni][r] * scale);
                }
    } else {
        // -------- fused V-transpose write (replaces vtrans kernel) --------
        const int b2  = m0 >> 11;              // batch (2048 rows each)
        const int h2  = (n0 + wn) >> 6;        // head for this quadrant
        const int t0l = (m0 & 2047) + wm;      // token base within batch
        unsigned short* Tr = SMEM + wave * 2368;   // per-wave [64][37] scratch
        const int d_sub = lane >> 3;           // 0..7
        const int tc    = lane & 7;            // 0..7
        unsigned short* VtH =
            Vtp + (size_t)((b2 * NH + h2) * DEPTH) * S_LEN;
#pragma unroll
        for (int ni = 0; ni < 2; ++ni) {
            // write phase: scatter f2bf(acc) into [t_local][d_local]
#pragma unroll
            for (int mi = 0; mi < 2; ++mi)
#pragma unroll
                for (int r = 0; r < 16; ++r) {
                    const int tl = mi * 32 + (r & 3) + 8 * (r >> 2) + 4 * s;
                    Tr[tl * 37 + l32] = f2bf(acc[mi][ni][r]);
                }
            asm volatile("s_waitcnt lgkmcnt(0)" ::: "memory");
            __builtin_amdgcn_sched_barrier(0);
            // read+store phase: 8 contiguous tokens per lane per d
#pragma unroll
            for (int di = 0; di < 4; ++di) {
                const int dl = d_sub + di * 8;     // 0..31 within chunk
                unsigned short tmp[8];
#pragma unroll
                for (int j = 0; j < 8; ++j)
                    tmp[j] = Tr[(tc * 8 + j) * 37 + dl];
                *(bf16x8*)&VtH[(size_t)(ni * 32 + dl) * S_LEN + t0l + tc * 8] =
                    *(const bf16x8*)tmp;
            }
            asm volatile("s_waitcnt lgkmcnt(0)" ::: "memory");
            __builtin_amdgcn_sched_barrier(0);
        }
    }
}

// ---------------------------------------------------------------------------
// Kernel 4 (R17): attention, key-split x2, register-P, LDS-staged K/V,
// 4 waves x 32 q rows, half-phase interleave.  NEW: T1 XCD-aware chunked
// block swizzle — 128 consecutive virtual ids (= 8 complete (h,z) K/V
// panels, 2 MB, L2-fit) per XCD.  Cuts the ~2.7x K/V HBM over-fetch and
// turns the drain-to-0 staging loads into L2 hits.
// ---------------------------------------------------------------------------
__global__ __launch_bounds__(256, 4)
void attn8_kernel(const unsigned short* __restrict__ Qp,
                  const unsigned short* __restrict__ Kp,
                  const unsigned short* __restrict__ Vt,
                  float* __restrict__ out,
                  float* __restrict__ Op1,
                  float* __restrict__ lp) {
    __shared__ __align__(16) char smem[32768];
    unsigned short* Ks = (unsigned short*)smem;              // [2][64*64] 16 KB
    unsigned short* Vs = (unsigned short*)(smem + 16384);    // [2][64*64] 16 KB

    const int tid  = threadIdx.x;
    const int w    = tid >> 6;          // 0..3
    const int lane = tid & 63;
    const int l32  = lane & 31;
    const int s    = lane >> 5;
    const int r8   = lane >> 3;
    const int sc   = (lane & 7) ^ r8;

    // XCD-aware swizzle: nwg = 16*16*4 = 1024 = 8 XCDs x 128.
    const int lin = blockIdx.x + (blockIdx.y << 4) + (blockIdx.z << 8);
    const int v   = ((lin & 7) << 7) + (lin >> 3);   // bijective
    const int qt  = v & 15;
    const int h   = (v >> 4) & 15;
    const int z   = v >> 8;

    const int q0 = qt * 128 + w * 32;   // 32 q rows per wave
    const int b     = z >> 1;
    const int split = z & 1;
    const int tbase = split * 1024;

    const unsigned short* Kg = Kp + (size_t)(b * S_LEN + tbase) * DM + h * DEPTH;
    const unsigned short* Vg = Vt + (size_t)((b * NH + h) * DEPTH) * S_LEN + tbase;
    float* obase = split ? Op1 : out;
    float* lbase = lp + (size_t)split * M_ROWS * NH;

    // Q B-frags (n = q, k = d = ch*16 + s*8 + j), prescaled by log2(e)/8
    bf16x8 qf[4];
    {
        const unsigned short* p =
            Qp + (size_t)(b * S_LEN + q0 + l32) * DM + h * DEPTH;
#pragma unroll
        for (int ch = 0; ch < 4; ++ch)
            qf[ch] = *(const bf16x8*)(p + ch * 16 + s * 8);
    }

    f32x16 oacc[2];   // [db]
    float lacc = 0.f;
#pragma unroll
    for (int db = 0; db < 2; ++db)
#pragma unroll
        for (int r = 0; r < 16; ++r) oacc[db][r] = 0.f;

    // prologue: each wave stages 16 K rows + 16 V rows of tile 0
#pragma unroll
    for (int i = 0; i < 2; ++i) {
        async_ld16(Kg + (size_t)(w * 16 + i * 8 + r8) * DM + sc * 8,
                   (char*)smem + w * 2048 + i * 1024);
        async_ld16(Vg + (size_t)(w * 16 + i * 8 + r8) * S_LEN + sc * 8,
                   (char*)smem + 16384 + w * 2048 + i * 1024);
    }

    for (int it = 0; it < 16; ++it) {
        const int cb = it & 1;

        // EXPLICIT per-wave drain of outstanding global_load_lds before the
        // barrier: after it, every wave's staged tile is visible to all.
        asm volatile("s_waitcnt vmcnt(0) lgkmcnt(0)" ::: "memory");
        __syncthreads();

        // prefetch next 64-key K+V tiles into cb^1 (hidden under compute)
        if (it < 15) {
            const int tn = (it + 1) * 64;
            char* kd = (char*)smem + (cb ^ 1) * 8192 + w * 2048;
            char* vd = (char*)smem + 16384 + (cb ^ 1) * 8192 + w * 2048;
#pragma unroll
            for (int i = 0; i < 2; ++i) {
                async_ld16(Kg + (size_t)(tn + w * 16 + i * 8 + r8) * DM + sc * 8,
                           kd + i * 1024);
                async_ld16(Vg + (size_t)(w * 16 + i * 8 + r8) * S_LEN + tn + sc * 8,
                           vd + i * 1024);
            }
        }

        const unsigned short* Kb = Ks + cb * 4096;
        const unsigned short* Vb = Vs + cb * 4096;

        // ---- phase 1: QK^T for BOTH 32-key halves, chains interleaved ----
        f32x16 sv0, sv1;
#pragma unroll
        for (int r = 0; r < 16; ++r) { sv0[r] = 0.f; sv1[r] = 0.f; }
        __builtin_amdgcn_s_setprio(1);
#pragma unroll
        for (int ch = 0; ch < 4; ++ch) {
            bf16x8 kf0 = *(const bf16x8*)
                &Kb[l32 * 64 + (((2 * ch + s) ^ (l32 & 7)) * 8)];
            bf16x8 kf1 = *(const bf16x8*)
                &Kb[2048 + l32 * 64 + (((2 * ch + s) ^ (l32 & 7)) * 8)];
            sv0 = __builtin_amdgcn_mfma_f32_32x32x16_bf16(kf0, qf[ch], sv0, 0, 0, 0);
            sv1 = __builtin_amdgcn_mfma_f32_32x32x16_bf16(kf1, qf[ch], sv1, 0, 0, 0);
        }
        __builtin_amdgcn_s_setprio(0);

        // ---- phase 2: softmax + pack for both halves ----
        unsigned pw[2][8];
#pragma unroll
        for (int th = 0; th < 2; ++th) {
            float p[16];
#pragma unroll
            for (int r = 0; r < 16; ++r)
                p[r] = __builtin_amdgcn_exp2f(th ? sv1[r] : sv0[r]);
            lacc += ((p[0] + p[1]) + (p[2] + p[3]))
                  + ((p[4] + p[5]) + (p[6] + p[7]))
                  + ((p[8] + p[9]) + (p[10] + p[11]))
                  + ((p[12] + p[13]) + (p[14] + p[15]));
            unsigned a0 = cvtpk_bf16(p[0],  p[1]);
            unsigned b0 = cvtpk_bf16(p[4],  p[5]);
            unsigned a1 = cvtpk_bf16(p[2],  p[3]);
            unsigned b1 = cvtpk_bf16(p[6],  p[7]);
            unsigned a2 = cvtpk_bf16(p[8],  p[9]);
            unsigned b2 = cvtpk_bf16(p[12], p[13]);
            unsigned a3 = cvtpk_bf16(p[10], p[11]);
            unsigned b3 = cvtpk_bf16(p[14], p[15]);
            permswap32(a0, b0);
            permswap32(a1, b1);
            permswap32(a2, b2);
            permswap32(a3, b3);
            pw[th][0] = a0; pw[th][1] = a1; pw[th][2] = b0; pw[th][3] = b1;
            pw[th][4] = a2; pw[th][5] = a3; pw[th][6] = b2; pw[th][7] = b3;
        }

        // ---- phase 3: PV for both halves ----
#pragma unroll
        for (int th = 0; th < 2; ++th) {
            const int vcb = th * 4;   // V col-chunk base
#pragma unroll
            for (int ch = 0; ch < 2; ++ch) {
                uint4 pu;
                pu.x = pw[th][ch * 4 + 0];
                pu.y = pw[th][ch * 4 + 1];
                pu.z = pw[th][ch * 4 + 2];
                pu.w = pw[th][ch * 4 + 3];
                bf16x8 pf = u4_to_bf8(pu);
                __builtin_amdgcn_s_setprio(1);
#pragma unroll
                for (int db = 0; db < 2; ++db) {
                    const int drow = db * 32 + l32;
                    bf16x8 vf = *(const bf16x8*)
                        &Vb[drow * 64 + (((vcb + 2 * ch + s) ^ (l32 & 7)) * 8)];
                    oacc[db] = __builtin_amdgcn_mfma_f32_32x32x16_bf16(
                        vf, pf, oacc[db], 0, 0, 0);
                }
                __builtin_amdgcn_s_setprio(0);
            }
        }
    }

    // no direct-to-LDS write may outlive the main loop
    asm volatile("s_waitcnt vmcnt(0)" ::: "memory");

    // l partial per q (t-halves live in opposite lane halves)
    const float l0 = lacc + __shfl_xor(lacc, 32, 64);
    if (s == 0)
        lbase[(size_t)(b * S_LEN + q0 + l32) * NH + h] = l0;

    // epilogue: unnormalized O^T -> LDS transpose (2 chunks of 16 q) ->
    // stores.  Per-wave scratch overlays staging (all waves past the final
    // barrier below; drain above guarantees no async write in flight).
    __syncthreads();
    float* Of = (float*)(smem + w * 4608);   // 16 q x 68 floats = 4352 B
#pragma unroll
    for (int c = 0; c < 2; ++c) {
        if ((l32 >> 4) == c) {
            const int qh = l32 & 15;
#pragma unroll
            for (int db = 0; db < 2; ++db)
#pragma unroll
                for (int m = 0; m < 4; ++m) {
                    float4 v4;
                    v4.x = oacc[db][4 * m + 0];
                    v4.y = oacc[db][4 * m + 1];
                    v4.z = oacc[db][4 * m + 2];
                    v4.w = oacc[db][4 * m + 3];
                    *(float4*)&Of[qh * 68 + db * 32 + 8 * m + 4 * s] = v4;
                }
        }
        asm volatile("" ::: "memory");
#pragma unroll
        for (int i = 0; i < 4; ++i) {
            const int row = i * 4 + (lane >> 4);
            const int c4 = lane & 15;
            float4 v4 = *(const float4*)&Of[row * 68 + c4 * 4];
            *(float4*)&obase[(size_t)(b * S_LEN + q0 + c * 16 + row) * DM
                             + h * DEPTH + c4 * 4] = v4;
        }
        asm volatile("" ::: "memory");
    }
}

// ---------------------------------------------------------------------------
// Kernel 5: combine the two key-splits: out = (O0 + O1) / (l0 + l1)
// ---------------------------------------------------------------------------
__global__ __launch_bounds__(256)
void combine_kernel(float* __restrict__ out, const float* __restrict__ Op1,
                    const float* __restrict__ lp) {
    const int i4 = blockIdx.x * 256 + threadIdx.x;   // [0, 1048576)
    const int row = i4 >> 8;
    const int c4  = i4 & 255;
    const int h   = c4 >> 4;
    const float l = lp[row * NH + h] + lp[M_ROWS * NH + row * NH + h];
    const float inv = 1.0f / l;
    float4 a = ((const float4*)out)[i4];
    float4 bq = ((const float4*)Op1)[i4];
    a.x = (a.x + bq.x) * inv;
    a.y = (a.y + bq.y) * inv;
    a.z = (a.z + bq.z) * inv;
    a.w = (a.w + bq.w) * inv;
    ((float4*)out)[i4] = a;
}

// ===========================================================================
// FALLBACK PATH (round-1 proven kernels, used only if ws is too small)
// ===========================================================================
#define LDK 72

__global__ __launch_bounds__(256)
void proj_gemm_kernel(const float* __restrict__ q, const float* __restrict__ k,
                      const float* __restrict__ v, const float* __restrict__ wq,
                      const float* __restrict__ wk, const float* __restrict__ wv,
                      unsigned short* __restrict__ Qp, unsigned short* __restrict__ Kp,
                      unsigned short* __restrict__ Vp) {
    __shared__ unsigned short As[128 * LDK];
    __shared__ unsigned short Bs[128 * LDK];

    const int z = blockIdx.z;
    const float* __restrict__ X = (z == 0) ? q : (z == 1) ? k : v;
    const float* __restrict__ W = (z == 0) ? wq : (z == 1) ? wk : wv;
    unsigned short* __restrict__ C = (z == 0) ? Qp : (z == 1) ? Kp : Vp;

    const int tid  = threadIdx.x;
    const int wave = tid >> 6;
    const int lane = tid & 63;
    const int quad = lane >> 4;
    const int l16  = lane & 15;
    const int m0 = blockIdx.x * 128;
    const int n0 = blockIdx.y * 128;
    const int wm = (wave >> 1) * 64;
    const int wn = (wave & 1) * 64;

    f32x4 acc[4][4];
#pragma unroll
    for (int mt = 0; mt < 4; ++mt)
#pragma unroll
        for (int nt = 0; nt < 4; ++nt)
            acc[mt][nt] = (f32x4){0.f, 0.f, 0.f, 0.f};

    for (int k0 = 0; k0 < DM; k0 += 64) {
#pragma unroll
        for (int vv = 0; vv < 8; ++vv) {
            int vecid = tid + 256 * vv;
            int r  = vecid >> 4;
            int c4 = vecid & 15;
            const float4 xa = *(const float4*)&X[(size_t)(m0 + r) * DM + k0 + c4 * 4];
            ushort4 pa;
            pa.x = f2bf(xa.x); pa.y = f2bf(xa.y); pa.z = f2bf(xa.z); pa.w = f2bf(xa.w);
            *(ushort4*)&As[r * LDK + c4 * 4] = pa;
            const float4 xb = *(const float4*)&W[(size_t)(n0 + r) * DM + k0 + c4 * 4];
            ushort4 pb;
            pb.x = f2bf(xb.x); pb.y = f2bf(xb.y); pb.z = f2bf(xb.z); pb.w = f2bf(xb.w);
            *(ushort4*)&Bs[r * LDK + c4 * 4] = pb;
        }
        __syncthreads();

#pragma unroll
        for (int kc = 0; kc < 2; ++kc) {
            bf16x8 af[4], bfr[4];
#pragma unroll
            for (int mt = 0; mt < 4; ++mt)
                af[mt] = *(const bf16x8*)&As[(wm + mt * 16 + l16) * LDK + kc * 32 + quad * 8];
#pragma unroll
            for (int nt = 0; nt < 4; ++nt)
                bfr[nt] = *(const bf16x8*)&Bs[(wn + nt * 16 + l16) * LDK + kc * 32 + quad * 8];
#pragma unroll
            for (int mt = 0; mt < 4; ++mt)
#pragma unroll
                for (int nt = 0; nt < 4; ++nt)
                    acc[mt][nt] = __builtin_amdgcn_mfma_f32_16x16x32_bf16(
                        af[mt], bfr[nt], acc[mt][nt], 0, 0, 0);
        }
        __syncthreads();
    }

#pragma unroll
    for (int mt = 0; mt < 4; ++mt)
#pragma unroll
        for (int nt = 0; nt < 4; ++nt)
#pragma unroll
            for (int r = 0; r < 4; ++r) {
                int row = m0 + wm + mt * 16 + quad * 4 + r;
                int col = n0 + wn + nt * 16 + l16;
                C[(size_t)row * DM + col] = f2bf(acc[mt][nt][r]);
            }
}

__global__ __launch_bounds__(256)
void attn_kernel(const unsigned short* __restrict__ Qp,
                 const unsigned short* __restrict__ Kp,
                 const unsigned short* __restrict__ Vp,
                 float* __restrict__ out) {
    __shared__ unsigned short Ks[64 * LDK];
    __shared__ unsigned short Vtl[64 * LDK];
    __shared__ unsigned short Ps[4 * 16 * LDK];

    const int tid  = threadIdx.x;
    const int wave = tid >> 6;
    const int lane = tid & 63;
    const int quad = lane >> 4;
    const int l16  = lane & 15;
    const int q0 = blockIdx.x * 64;
    const int h  = blockIdx.y;
    const int b  = blockIdx.z;
    const int wbase = wave * 16 * LDK;

    bf16x8 qf[2];
    {
        size_t row = (size_t)b * S_LEN + q0 + wave * 16 + l16;
        const unsigned short* p = Qp + row * DM + h * DEPTH;
        qf[0] = *(const bf16x8*)(p + quad * 8);
        qf[1] = *(const bf16x8*)(p + 32 + quad * 8);
    }

    float m_i[4], l_i[4];
    f32x4 accO[4];
#pragma unroll
    for (int r = 0; r < 4; ++r) { m_i[r] = -1e30f; l_i[r] = 0.f; }
#pragma unroll
    for (int f = 0; f < 4; ++f) accO[f] = (f32x4){0.f, 0.f, 0.f, 0.f};

    for (int t0 = 0; t0 < S_LEN; t0 += 64) {
#pragma unroll
        for (int vv = 0; vv < 2; ++vv) {
            int vecid = tid + 256 * vv;
            int r  = vecid >> 3;
            int cv = vecid & 7;
            size_t grow = (size_t)(b * S_LEN + t0 + r) * DM + h * DEPTH + cv * 8;
            *(bf16x8*)&Ks[r * LDK + cv * 8] = *(const bf16x8*)(Kp + grow);
            bf16x8 vvv = *(const bf16x8*)(Vp + grow);
#pragma unroll
            for (int j = 0; j < 8; ++j)
                Vtl[(cv * 8 + j) * LDK + r] = ((const unsigned short*)&vvv)[j];
        }
        __syncthreads();

        f32x4 sc4[4];
#pragma unroll
        for (int nt = 0; nt < 4; ++nt) {
            f32x4 a = (f32x4){0.f, 0.f, 0.f, 0.f};
            bf16x8 kf0 = *(const bf16x8*)&Ks[(nt * 16 + l16) * LDK + quad * 8];
            bf16x8 kf1 = *(const bf16x8*)&Ks[(nt * 16 + l16) * LDK + 32 + quad * 8];
            a = __builtin_amdgcn_mfma_f32_16x16x32_bf16(qf[0], kf0, a, 0, 0, 0);
            a = __builtin_amdgcn_mfma_f32_16x16x32_bf16(qf[1], kf1, a, 0, 0, 0);
            sc4[nt] = a;
        }
#pragma unroll
        for (int nt = 0; nt < 4; ++nt)
#pragma unroll
            for (int r = 0; r < 4; ++r) sc4[nt][r] *= 0.125f;

#pragma unroll
        for (int r = 0; r < 4; ++r) {
            float mx = fmaxf(fmaxf(sc4[0][r], sc4[1][r]), fmaxf(sc4[2][r], sc4[3][r]));
#pragma unroll
            for (int off = 1; off < 16; off <<= 1)
                mx = fmaxf(mx, __shfl_xor(mx, off, 64));
            float mnew = fmaxf(m_i[r], mx);
            float alpha = __expf(m_i[r] - mnew);
            float rs = 0.f;
#pragma unroll
            for (int nt = 0; nt < 4; ++nt) {
                float p = __expf(sc4[nt][r] - mnew);
                sc4[nt][r] = p;
                rs += p;
            }
#pragma unroll
            for (int off = 1; off < 16; off <<= 1)
                rs += __shfl_xor(rs, off, 64);
            l_i[r] = l_i[r] * alpha + rs;
            m_i[r] = mnew;
#pragma unroll
            for (int f = 0; f < 4; ++f) accO[f][r] *= alpha;
        }

#pragma unroll
        for (int nt = 0; nt < 4; ++nt)
#pragma unroll
            for (int r = 0; r < 4; ++r)
                Ps[wbase + (quad * 4 + r) * LDK + nt * 16 + l16] = f2bf(sc4[nt][r]);
        __syncthreads();

        bf16x8 pf0 = *(const bf16x8*)&Ps[wbase + l16 * LDK + quad * 8];
        bf16x8 pf1 = *(const bf16x8*)&Ps[wbase + l16 * LDK + 32 + quad * 8];
#pragma unroll
        for (int f = 0; f < 4; ++f) {
            bf16x8 vf0 = *(const bf16x8*)&Vtl[(f * 16 + l16) * LDK + quad * 8];
            bf16x8 vf1 = *(const bf16x8*)&Vtl[(f * 16 + l16) * LDK + 32 + quad * 8];
            accO[f] = __builtin_amdgcn_mfma_f32_16x16x32_bf16(pf0, vf0, accO[f], 0, 0, 0);
            accO[f] = __builtin_amdgcn_mfma_f32_16x16x32_bf16(pf1, vf1, accO[f], 0, 0, 0);
        }
        __syncthreads();
    }

#pragma unroll
    for (int f = 0; f < 4; ++f)
#pragma unroll
        for (int r = 0; r < 4; ++r) {
            size_t row = (size_t)b * S_LEN + q0 + wave * 16 + quad * 4 + r;
            out[row * DM + h * DEPTH + f * 16 + l16] = accO[f][r] / l_i[r];
        }
}

// ---------------------------------------------------------------------------
extern "C" void kernel_launch(void* const* d_in, const int* in_sizes, int n_in,
                              void* d_out, int out_size, void* d_ws, size_t ws_size,
                              hipStream_t stream) {
    const float* q  = (const float*)d_in[0];
    const float* k  = (const float*)d_in[1];
    const float* v  = (const float*)d_in[2];
    const float* wq = (const float*)d_in[3];
    const float* wk = (const float*)d_in[4];
    const float* wv = (const float*)d_in[5];
    float* out = (float*)d_out;

    unsigned short* ws = (unsigned short*)d_ws;
    const size_t NPROJ = (size_t)M_ROWS * DM;   // 4,194,304
    const size_t NW    = (size_t)DM * DM;       // 1,048,576

    // fast path ws layout (ushort elements):
    //   region A [0, 3*NPROJ):       Xbf (q,k,v) during proj; then
    //                                Op1(fp32) at [NPROJ,3*NPROJ)
    //   region B [3NP, 3NP+3NW):     Wbf during proj; then lp (fp32, 512 KB)
    //   region C [3NP+3NW, +3NPROJ): Qp, Kp, Vt (Vt written by fused proj)
    const size_t need = (3 * NPROJ + 3 * NW + 3 * NPROJ) * sizeof(unsigned short);

    if (ws_size >= need) {
        unsigned short* Xbf = ws;
        unsigned short* Wbf = ws + 3 * NPROJ;
        unsigned short* Cp  = ws + 3 * NPROJ + 3 * NW;
        unsigned short* Qp  = Cp;
        unsigned short* Kp  = Cp + NPROJ;
        unsigned short* Vt  = Cp + 2 * NPROJ;        // old Vp slot, Vt layout
        float*          Op1 = (float*)(ws + NPROJ);  // overlays Xbf(k,v)
        float*          lp  = (float*)(ws + 3 * NPROJ);  // overlays Wbf

        convert_kernel<<<dim3(256, 6), 256, 0, stream>>>(q, k, v, wq, wk, wv, Xbf);
        proj_gemm3_kernel<<<dim3(M_ROWS / 128, DM / 128, 3), 256, 0, stream>>>(
            Xbf, Wbf, Cp, Vt);
        attn8_kernel<<<dim3(S_LEN / 128, NH, 4), 256, 0, stream>>>(
            Qp, Kp, Vt, out, Op1, lp);
        combine_kernel<<<dim3(M_ROWS * DM / 4 / 256), 256, 0, stream>>>(out, Op1, lp);
    } else {
        unsigned short* Qp = ws;
        unsigned short* Kp = ws + NPROJ;
        unsigned short* Vp = ws + 2 * NPROJ;
        proj_gemm_kernel<<<dim3(M_ROWS / 128, DM / 128, 3), 256, 0, stream>>>(
            q, k, v, wq, wk, wv, Qp, Kp, Vp);
        attn_kernel<<<dim3(S_LEN / 64, NH, B_SZ), 256, 0, stream>>>(Qp, Kp, Vp, out);
    }
}

// Round 13
// 186.489 us; speedup vs baseline: 1.0741x; 1.0741x over previous
//
#include <hip/hip_runtime.h>
#include <hip/hip_bf16.h>
#include <stdint.h>

// Sizes (fixed by the problem)
#define B_SZ 2
#define S_LEN 2048
#define DM 1024
#define NH 16
#define DEPTH 64
#define M_ROWS (B_SZ * S_LEN)   // 4096
#define SCALE_Q 0.1803368801111144f   // log2(e)/sqrt(DEPTH), folded into Q proj

typedef __attribute__((ext_vector_type(8))) short bf16x8;    // 8 bf16 = 4 VGPRs
typedef __attribute__((ext_vector_type(4))) float f32x4;     // 16x16 C/D frag
typedef __attribute__((ext_vector_type(16))) float f32x16;   // 32x32 C/D frag

__device__ __forceinline__ unsigned short f2bf(float x) {
    union { float f; unsigned u; } a; a.f = x;
    unsigned r = a.u + 0x7FFF + ((a.u >> 16) & 1);   // RTNE
    return (unsigned short)(r >> 16);
}

__device__ __forceinline__ bf16x8 u4_to_bf8(uint4 u) {
    union { uint4 a; bf16x8 b; } c; c.a = u; return c.b;   // value bitcast
}

// v_cvt_pk_bf16_f32: D.lo = bf16(lo), D.hi = bf16(hi)  (RTNE). No builtin on
// gfx950 -> inline asm.
__device__ __forceinline__ unsigned cvtpk_bf16(float lo, float hi) {
    unsigned r;
    asm("v_cvt_pk_bf16_f32 %0, %1, %2" : "=v"(r) : "v"(lo), "v"(hi));
    return r;
}

// v_permlane32_swap_b32: a[hi lanes] <- b_old[lo lanes]; b[lo lanes] <-
// a_old[hi lanes]; a[lo], b[hi] unchanged.
__device__ __forceinline__ void permswap32(unsigned &a, unsigned &b) {
    auto r = __builtin_amdgcn_permlane32_swap(a, b, false, false);
    a = r[0]; b = r[1];
}

// async global->LDS, 16B per lane. LDS dest = wave-uniform base + lane*16.
__device__ __forceinline__ void async_ld16(const unsigned short* g, void* l) {
    __builtin_amdgcn_global_load_lds(
        (const __attribute__((address_space(1))) void*)g,
        (__attribute__((address_space(3))) void*)l,
        16, 0, 0);
}

// ===========================================================================
// FAST PATH
// ===========================================================================

// ---------------------------------------------------------------------------
// Kernel 1: fp32 -> bf16 convert (RTNE) of q,k,v,wq,wk,wv into ws.
// ---------------------------------------------------------------------------
__global__ __launch_bounds__(256)
void convert_kernel(const float* __restrict__ q, const float* __restrict__ k,
                    const float* __restrict__ v, const float* __restrict__ wq,
                    const float* __restrict__ wk, const float* __restrict__ wv,
                    unsigned short* __restrict__ dst) {
    const int z = blockIdx.y;
    const float* src = (z == 0) ? q : (z == 1) ? k : (z == 2) ? v
                     : (z == 3) ? wq : (z == 4) ? wk : wv;
    const size_t n4  = (z < 3) ? ((size_t)M_ROWS * DM / 4) : ((size_t)DM * DM / 4);
    const size_t off = (z < 3) ? ((size_t)z * M_ROWS * DM)
                               : ((size_t)3 * M_ROWS * DM + (size_t)(z - 3) * DM * DM);
    unsigned short* d = dst + off;
    const size_t stride = (size_t)gridDim.x * blockDim.x;
    for (size_t i = (size_t)blockIdx.x * blockDim.x + threadIdx.x; i < n4; i += stride) {
        float4 x = ((const float4*)src)[i];
        ushort4 p;
        p.x = f2bf(x.x); p.y = f2bf(x.y); p.z = f2bf(x.z); p.w = f2bf(x.w);
        ((ushort4*)d)[i] = p;
    }
}

// ---------------------------------------------------------------------------
// Kernel 2 (R18): bf16 NT GEMM, 128x128 tile, BK=64, global_load_lds,
// XOR-swizzled LDS, fused V-transpose epilogue (z==2 writes Vt directly).
// Changes vs R17: (a) proj XCD swizzle REVERTED to linear (R17's variant
// gave each XCD the full X panel — worse locality, ~+5 µs); (b) DOUBLE-
// BUFFERED staging (attn8-proven loop): prologue stages tile 0; each
// iteration prefetches tile k+1 into buf^1 while computing buf.  LDS 64 KB
// (As[2]|Bs[2]).  Removes the per-K-step full load-latency exposure that
// R17's counters showed (MfmaUtil 20%, VALUBusy 10% = idle waves).
// V-transpose scratch relocated to the dead As0/Bs0 regions.
// ---------------------------------------------------------------------------
__global__ __launch_bounds__(256)
void proj_gemm3_kernel(const unsigned short* __restrict__ Xall,
                       const unsigned short* __restrict__ Wall,
                       unsigned short* __restrict__ Call,
                       unsigned short* __restrict__ Vtp) {
    // ushort layout: As0 [0,8192) | As1 [8192,16384) | Bs0 [16384,24576) |
    // Bs1 [24576,32768)   (byte offsets x2)
    __shared__ unsigned short SMEM[4 * 128 * 64];   // 64 KB

    const int z = blockIdx.z;
    const unsigned short* X = Xall + (size_t)z * M_ROWS * DM;
    const unsigned short* W = Wall + (size_t)z * DM * DM;
    unsigned short* C = Call + (size_t)z * M_ROWS * DM;

    const int tid  = threadIdx.x;
    const int wave = tid >> 6;
    const int lane = tid & 63;
    const int l32  = lane & 31;
    const int s    = lane >> 5;
    const int m0 = blockIdx.x * 128;
    const int n0 = blockIdx.y * 128;
    const int wm = (wave >> 1) * 64;
    const int wn = (wave & 1) * 64;

    const int r8 = lane >> 3;
    const int sc = (lane & 7) ^ r8;

    f32x16 acc[2][2];
#pragma unroll
    for (int mi = 0; mi < 2; ++mi)
#pragma unroll
        for (int ni = 0; ni < 2; ++ni)
#pragma unroll
            for (int r = 0; r < 16; ++r) acc[mi][ni][r] = 0.f;

    // prologue: stage K-tile 0 into buffer 0
#pragma unroll
    for (int i = 0; i < 4; ++i) {
        const int r = i * 32 + wave * 8 + r8;
        async_ld16(X + (size_t)(m0 + r) * DM + sc * 8,
                   (char*)SMEM + i * 4096 + wave * 1024);
        async_ld16(W + (size_t)(n0 + r) * DM + sc * 8,
                   (char*)SMEM + 32768 + i * 4096 + wave * 1024);
    }

    for (int kk = 0; kk < 16; ++kk) {
        const int cb = kk & 1;

        // per-wave drain of outstanding global_load_lds, then publish
        asm volatile("s_waitcnt vmcnt(0) lgkmcnt(0)" ::: "memory");
        __syncthreads();

        // prefetch next K-tile into cb^1 (hidden under this tile's compute)
        if (kk < 15) {
            const int k0 = (kk + 1) * 64;
            char* ad = (char*)SMEM + (cb ^ 1) * 16384;
            char* bd = (char*)SMEM + 32768 + (cb ^ 1) * 16384;
#pragma unroll
            for (int i = 0; i < 4; ++i) {
                const int r = i * 32 + wave * 8 + r8;
                async_ld16(X + (size_t)(m0 + r) * DM + k0 + sc * 8,
                           ad + i * 4096 + wave * 1024);
                async_ld16(W + (size_t)(n0 + r) * DM + k0 + sc * 8,
                           bd + i * 4096 + wave * 1024);
            }
        }

        const unsigned short* As = SMEM + cb * 8192;
        const unsigned short* Bs = SMEM + 16384 + cb * 8192;

#pragma unroll
        for (int ch = 0; ch < 4; ++ch) {
            bf16x8 af[2], bfr[2];
#pragma unroll
            for (int mi = 0; mi < 2; ++mi) {
                const int row = wm + mi * 32 + l32;
                af[mi] = *(const bf16x8*)&As[row * 64 + (((2 * ch + s) ^ (row & 7)) * 8)];
            }
#pragma unroll
            for (int ni = 0; ni < 2; ++ni) {
                const int row = wn + ni * 32 + l32;
                bfr[ni] = *(const bf16x8*)&Bs[row * 64 + (((2 * ch + s) ^ (row & 7)) * 8)];
            }
#pragma unroll
            for (int mi = 0; mi < 2; ++mi)
#pragma unroll
                for (int ni = 0; ni < 2; ++ni)
                    acc[mi][ni] = __builtin_amdgcn_mfma_f32_32x32x16_bf16(
                        af[mi], bfr[ni], acc[mi][ni], 0, 0, 0);
        }
    }

    if (z < 2) {
        const float scale = (z == 0) ? SCALE_Q : 1.0f;
#pragma unroll
        for (int mi = 0; mi < 2; ++mi)
#pragma unroll
            for (int ni = 0; ni < 2; ++ni)
#pragma unroll
                for (int r = 0; r < 16; ++r) {
                    const int row = m0 + wm + mi * 32 + (r & 3) + 8 * (r >> 2) + 4 * s;
                    const int col = n0 + wn + ni * 32 + l32;
                    C[(size_t)row * DM + col] = f2bf(acc[mi][ni][r] * scale);
                }
    } else {
        // -------- fused V-transpose write (replaces vtrans kernel) --------
        // Scratch lives in As0 (waves 0-1) / Bs0 (waves 2-3): last compute
        // read only buf1, and every wave passed the kk=15 barrier after its
        // final buf0 reads -> buf0 is dead.  Wave-internal ds ordering
        // pinned by lgkmcnt(0) + sched_barrier(0) (rule #18).
        const int b2  = m0 >> 11;              // batch (2048 rows each)
        const int h2  = (n0 + wn) >> 6;        // head for this quadrant
        const int t0l = (m0 & 2047) + wm;      // token base within batch
        unsigned short* Tr = SMEM + (wave >> 1) * 16384 + (wave & 1) * 2368;
        const int d_sub = lane >> 3;           // 0..7
        const int tc    = lane & 7;            // 0..7
        unsigned short* VtH =
            Vtp + (size_t)((b2 * NH + h2) * DEPTH) * S_LEN;
#pragma unroll
        for (int ni = 0; ni < 2; ++ni) {
            // write phase: scatter f2bf(acc) into [t_local][d_local]
#pragma unroll
            for (int mi = 0; mi < 2; ++mi)
#pragma unroll
                for (int r = 0; r < 16; ++r) {
                    const int tl = mi * 32 + (r & 3) + 8 * (r >> 2) + 4 * s;
                    Tr[tl * 37 + l32] = f2bf(acc[mi][ni][r]);
                }
            asm volatile("s_waitcnt lgkmcnt(0)" ::: "memory");
            __builtin_amdgcn_sched_barrier(0);
            // read+store phase: 8 contiguous tokens per lane per d
#pragma unroll
            for (int di = 0; di < 4; ++di) {
                const int dl = d_sub + di * 8;     // 0..31 within chunk
                unsigned short tmp[8];
#pragma unroll
                for (int j = 0; j < 8; ++j)
                    tmp[j] = Tr[(tc * 8 + j) * 37 + dl];
                *(bf16x8*)&VtH[(size_t)(ni * 32 + dl) * S_LEN + t0l + tc * 8] =
                    *(const bf16x8*)tmp;
            }
            asm volatile("s_waitcnt lgkmcnt(0)" ::: "memory");
            __builtin_amdgcn_sched_barrier(0);
        }
    }
}

// ---------------------------------------------------------------------------
// Kernel 4 (R17, unchanged): attention, key-split x2, register-P, LDS-staged
// K/V, 4 waves x 32 q rows, half-phase interleave, XCD-aware block swizzle
// (128 consecutive virtual ids = 8 complete (h,z) K/V panels per XCD).
// ---------------------------------------------------------------------------
__global__ __launch_bounds__(256, 4)
void attn8_kernel(const unsigned short* __restrict__ Qp,
                  const unsigned short* __restrict__ Kp,
                  const unsigned short* __restrict__ Vt,
                  float* __restrict__ out,
                  float* __restrict__ Op1,
                  float* __restrict__ lp) {
    __shared__ __align__(16) char smem[32768];
    unsigned short* Ks = (unsigned short*)smem;              // [2][64*64] 16 KB
    unsigned short* Vs = (unsigned short*)(smem + 16384);    // [2][64*64] 16 KB

    const int tid  = threadIdx.x;
    const int w    = tid >> 6;          // 0..3
    const int lane = tid & 63;
    const int l32  = lane & 31;
    const int s    = lane >> 5;
    const int r8   = lane >> 3;
    const int sc   = (lane & 7) ^ r8;

    // XCD-aware swizzle: nwg = 16*16*4 = 1024 = 8 XCDs x 128.
    const int lin = blockIdx.x + (blockIdx.y << 4) + (blockIdx.z << 8);
    const int v   = ((lin & 7) << 7) + (lin >> 3);   // bijective
    const int qt  = v & 15;
    const int h   = (v >> 4) & 15;
    const int z   = v >> 8;

    const int q0 = qt * 128 + w * 32;   // 32 q rows per wave
    const int b     = z >> 1;
    const int split = z & 1;
    const int tbase = split * 1024;

    const unsigned short* Kg = Kp + (size_t)(b * S_LEN + tbase) * DM + h * DEPTH;
    const unsigned short* Vg = Vt + (size_t)((b * NH + h) * DEPTH) * S_LEN + tbase;
    float* obase = split ? Op1 : out;
    float* lbase = lp + (size_t)split * M_ROWS * NH;

    // Q B-frags (n = q, k = d = ch*16 + s*8 + j), prescaled by log2(e)/8
    bf16x8 qf[4];
    {
        const unsigned short* p =
            Qp + (size_t)(b * S_LEN + q0 + l32) * DM + h * DEPTH;
#pragma unroll
        for (int ch = 0; ch < 4; ++ch)
            qf[ch] = *(const bf16x8*)(p + ch * 16 + s * 8);
    }

    f32x16 oacc[2];   // [db]
    float lacc = 0.f;
#pragma unroll
    for (int db = 0; db < 2; ++db)
#pragma unroll
        for (int r = 0; r < 16; ++r) oacc[db][r] = 0.f;

    // prologue: each wave stages 16 K rows + 16 V rows of tile 0
#pragma unroll
    for (int i = 0; i < 2; ++i) {
        async_ld16(Kg + (size_t)(w * 16 + i * 8 + r8) * DM + sc * 8,
                   (char*)smem + w * 2048 + i * 1024);
        async_ld16(Vg + (size_t)(w * 16 + i * 8 + r8) * S_LEN + sc * 8,
                   (char*)smem + 16384 + w * 2048 + i * 1024);
    }

    for (int it = 0; it < 16; ++it) {
        const int cb = it & 1;

        // EXPLICIT per-wave drain of outstanding global_load_lds before the
        // barrier: after it, every wave's staged tile is visible to all.
        asm volatile("s_waitcnt vmcnt(0) lgkmcnt(0)" ::: "memory");
        __syncthreads();

        // prefetch next 64-key K+V tiles into cb^1 (hidden under compute)
        if (it < 15) {
            const int tn = (it + 1) * 64;
            char* kd = (char*)smem + (cb ^ 1) * 8192 + w * 2048;
            char* vd = (char*)smem + 16384 + (cb ^ 1) * 8192 + w * 2048;
#pragma unroll
            for (int i = 0; i < 2; ++i) {
                async_ld16(Kg + (size_t)(tn + w * 16 + i * 8 + r8) * DM + sc * 8,
                           kd + i * 1024);
                async_ld16(Vg + (size_t)(w * 16 + i * 8 + r8) * S_LEN + tn + sc * 8,
                           vd + i * 1024);
            }
        }

        const unsigned short* Kb = Ks + cb * 4096;
        const unsigned short* Vb = Vs + cb * 4096;

        // ---- phase 1: QK^T for BOTH 32-key halves, chains interleaved ----
        f32x16 sv0, sv1;
#pragma unroll
        for (int r = 0; r < 16; ++r) { sv0[r] = 0.f; sv1[r] = 0.f; }
        __builtin_amdgcn_s_setprio(1);
#pragma unroll
        for (int ch = 0; ch < 4; ++ch) {
            bf16x8 kf0 = *(const bf16x8*)
                &Kb[l32 * 64 + (((2 * ch + s) ^ (l32 & 7)) * 8)];
            bf16x8 kf1 = *(const bf16x8*)
                &Kb[2048 + l32 * 64 + (((2 * ch + s) ^ (l32 & 7)) * 8)];
            sv0 = __builtin_amdgcn_mfma_f32_32x32x16_bf16(kf0, qf[ch], sv0, 0, 0, 0);
            sv1 = __builtin_amdgcn_mfma_f32_32x32x16_bf16(kf1, qf[ch], sv1, 0, 0, 0);
        }
        __builtin_amdgcn_s_setprio(0);

        // ---- phase 2: softmax + pack for both halves ----
        unsigned pw[2][8];
#pragma unroll
        for (int th = 0; th < 2; ++th) {
            float p[16];
#pragma unroll
            for (int r = 0; r < 16; ++r)
                p[r] = __builtin_amdgcn_exp2f(th ? sv1[r] : sv0[r]);
            lacc += ((p[0] + p[1]) + (p[2] + p[3]))
                  + ((p[4] + p[5]) + (p[6] + p[7]))
                  + ((p[8] + p[9]) + (p[10] + p[11]))
                  + ((p[12] + p[13]) + (p[14] + p[15]));
            unsigned a0 = cvtpk_bf16(p[0],  p[1]);
            unsigned b0 = cvtpk_bf16(p[4],  p[5]);
            unsigned a1 = cvtpk_bf16(p[2],  p[3]);
            unsigned b1 = cvtpk_bf16(p[6],  p[7]);
            unsigned a2 = cvtpk_bf16(p[8],  p[9]);
            unsigned b2 = cvtpk_bf16(p[12], p[13]);
            unsigned a3 = cvtpk_bf16(p[10], p[11]);
            unsigned b3 = cvtpk_bf16(p[14], p[15]);
            permswap32(a0, b0);
            permswap32(a1, b1);
            permswap32(a2, b2);
            permswap32(a3, b3);
            pw[th][0] = a0; pw[th][1] = a1; pw[th][2] = b0; pw[th][3] = b1;
            pw[th][4] = a2; pw[th][5] = a3; pw[th][6] = b2; pw[th][7] = b3;
        }

        // ---- phase 3: PV for both halves ----
#pragma unroll
        for (int th = 0; th < 2; ++th) {
            const int vcb = th * 4;   // V col-chunk base
#pragma unroll
            for (int ch = 0; ch < 2; ++ch) {
                uint4 pu;
                pu.x = pw[th][ch * 4 + 0];
                pu.y = pw[th][ch * 4 + 1];
                pu.z = pw[th][ch * 4 + 2];
                pu.w = pw[th][ch * 4 + 3];
                bf16x8 pf = u4_to_bf8(pu);
                __builtin_amdgcn_s_setprio(1);
#pragma unroll
                for (int db = 0; db < 2; ++db) {
                    const int drow = db * 32 + l32;
                    bf16x8 vf = *(const bf16x8*)
                        &Vb[drow * 64 + (((vcb + 2 * ch + s) ^ (l32 & 7)) * 8)];
                    oacc[db] = __builtin_amdgcn_mfma_f32_32x32x16_bf16(
                        vf, pf, oacc[db], 0, 0, 0);
                }
                __builtin_amdgcn_s_setprio(0);
            }
        }
    }

    // no direct-to-LDS write may outlive the main loop
    asm volatile("s_waitcnt vmcnt(0)" ::: "memory");

    // l partial per q (t-halves live in opposite lane halves)
    const float l0 = lacc + __shfl_xor(lacc, 32, 64);
    if (s == 0)
        lbase[(size_t)(b * S_LEN + q0 + l32) * NH + h] = l0;

    // epilogue: unnormalized O^T -> LDS transpose (2 chunks of 16 q) ->
    // stores.  Per-wave scratch overlays staging (all waves past the final
    // barrier below; drain above guarantees no async write in flight).
    __syncthreads();
    float* Of = (float*)(smem + w * 4608);   // 16 q x 68 floats = 4352 B
#pragma unroll
    for (int c = 0; c < 2; ++c) {
        if ((l32 >> 4) == c) {
            const int qh = l32 & 15;
#pragma unroll
            for (int db = 0; db < 2; ++db)
#pragma unroll
                for (int m = 0; m < 4; ++m) {
                    float4 v4;
                    v4.x = oacc[db][4 * m + 0];
                    v4.y = oacc[db][4 * m + 1];
                    v4.z = oacc[db][4 * m + 2];
                    v4.w = oacc[db][4 * m + 3];
                    *(float4*)&Of[qh * 68 + db * 32 + 8 * m + 4 * s] = v4;
                }
        }
        asm volatile("" ::: "memory");
#pragma unroll
        for (int i = 0; i < 4; ++i) {
            const int row = i * 4 + (lane >> 4);
            const int c4 = lane & 15;
            float4 v4 = *(const float4*)&Of[row * 68 + c4 * 4];
            *(float4*)&obase[(size_t)(b * S_LEN + q0 + c * 16 + row) * DM
                             + h * DEPTH + c4 * 4] = v4;
        }
        asm volatile("" ::: "memory");
    }
}

// ---------------------------------------------------------------------------
// Kernel 5: combine the two key-splits: out = (O0 + O1) / (l0 + l1)
// ---------------------------------------------------------------------------
__global__ __launch_bounds__(256)
void combine_kernel(float* __restrict__ out, const float* __restrict__ Op1,
                    const float* __restrict__ lp) {
    const int i4 = blockIdx.x * 256 + threadIdx.x;   // [0, 1048576)
    const int row = i4 >> 8;
    const int c4  = i4 & 255;
    const int h   = c4 >> 4;
    const float l = lp[row * NH + h] + lp[M_ROWS * NH + row * NH + h];
    const float inv = 1.0f / l;
    float4 a = ((const float4*)out)[i4];
    float4 bq = ((const float4*)Op1)[i4];
    a.x = (a.x + bq.x) * inv;
    a.y = (a.y + bq.y) * inv;
    a.z = (a.z + bq.z) * inv;
    a.w = (a.w + bq.w) * inv;
    ((float4*)out)[i4] = a;
}

// ===========================================================================
// FALLBACK PATH (round-1 proven kernels, used only if ws is too small)
// ===========================================================================
#define LDK 72

__global__ __launch_bounds__(256)
void proj_gemm_kernel(const float* __restrict__ q, const float* __restrict__ k,
                      const float* __restrict__ v, const float* __restrict__ wq,
                      const float* __restrict__ wk, const float* __restrict__ wv,
                      unsigned short* __restrict__ Qp, unsigned short* __restrict__ Kp,
                      unsigned short* __restrict__ Vp) {
    __shared__ unsigned short As[128 * LDK];
    __shared__ unsigned short Bs[128 * LDK];

    const int z = blockIdx.z;
    const float* __restrict__ X = (z == 0) ? q : (z == 1) ? k : v;
    const float* __restrict__ W = (z == 0) ? wq : (z == 1) ? wk : wv;
    unsigned short* __restrict__ C = (z == 0) ? Qp : (z == 1) ? Kp : Vp;

    const int tid  = threadIdx.x;
    const int wave = tid >> 6;
    const int lane = tid & 63;
    const int quad = lane >> 4;
    const int l16  = lane & 15;
    const int m0 = blockIdx.x * 128;
    const int n0 = blockIdx.y * 128;
    const int wm = (wave >> 1) * 64;
    const int wn = (wave & 1) * 64;

    f32x4 acc[4][4];
#pragma unroll
    for (int mt = 0; mt < 4; ++mt)
#pragma unroll
        for (int nt = 0; nt < 4; ++nt)
            acc[mt][nt] = (f32x4){0.f, 0.f, 0.f, 0.f};

    for (int k0 = 0; k0 < DM; k0 += 64) {
#pragma unroll
        for (int vv = 0; vv < 8; ++vv) {
            int vecid = tid + 256 * vv;
            int r  = vecid >> 4;
            int c4 = vecid & 15;
            const float4 xa = *(const float4*)&X[(size_t)(m0 + r) * DM + k0 + c4 * 4];
            ushort4 pa;
            pa.x = f2bf(xa.x); pa.y = f2bf(xa.y); pa.z = f2bf(xa.z); pa.w = f2bf(xa.w);
            *(ushort4*)&As[r * LDK + c4 * 4] = pa;
            const float4 xb = *(const float4*)&W[(size_t)(n0 + r) * DM + k0 + c4 * 4];
            ushort4 pb;
            pb.x = f2bf(xb.x); pb.y = f2bf(xb.y); pb.z = f2bf(xb.z); pb.w = f2bf(xb.w);
            *(ushort4*)&Bs[r * LDK + c4 * 4] = pb;
        }
        __syncthreads();

#pragma unroll
        for (int kc = 0; kc < 2; ++kc) {
            bf16x8 af[4], bfr[4];
#pragma unroll
            for (int mt = 0; mt < 4; ++mt)
                af[mt] = *(const bf16x8*)&As[(wm + mt * 16 + l16) * LDK + kc * 32 + quad * 8];
#pragma unroll
            for (int nt = 0; nt < 4; ++nt)
                bfr[nt] = *(const bf16x8*)&Bs[(wn + nt * 16 + l16) * LDK + kc * 32 + quad * 8];
#pragma unroll
            for (int mt = 0; mt < 4; ++mt)
#pragma unroll
                for (int nt = 0; nt < 4; ++nt)
                    acc[mt][nt] = __builtin_amdgcn_mfma_f32_16x16x32_bf16(
                        af[mt], bfr[nt], acc[mt][nt], 0, 0, 0);
        }
        __syncthreads();
    }

#pragma unroll
    for (int mt = 0; mt < 4; ++mt)
#pragma unroll
        for (int nt = 0; nt < 4; ++nt)
#pragma unroll
            for (int r = 0; r < 4; ++r) {
                int row = m0 + wm + mt * 16 + quad * 4 + r;
                int col = n0 + wn + nt * 16 + l16;
                C[(size_t)row * DM + col] = f2bf(acc[mt][nt][r]);
            }
}

__global__ __launch_bounds__(256)
void attn_kernel(const unsigned short* __restrict__ Qp,
                 const unsigned short* __restrict__ Kp,
                 const unsigned short* __restrict__ Vp,
                 float* __restrict__ out) {
    __shared__ unsigned short Ks[64 * LDK];
    __shared__ unsigned short Vtl[64 * LDK];
    __shared__ unsigned short Ps[4 * 16 * LDK];

    const int tid  = threadIdx.x;
    const int wave = tid >> 6;
    const int lane = tid & 63;
    const int quad = lane >> 4;
    const int l16  = lane & 15;
    const int q0 = blockIdx.x * 64;
    const int h  = blockIdx.y;
    const int b  = blockIdx.z;
    const int wbase = wave * 16 * LDK;

    bf16x8 qf[2];
    {
        size_t row = (size_t)b * S_LEN + q0 + wave * 16 + l16;
        const unsigned short* p = Qp + row * DM + h * DEPTH;
        qf[0] = *(const bf16x8*)(p + quad * 8);
        qf[1] = *(const bf16x8*)(p + 32 + quad * 8);
    }

    float m_i[4], l_i[4];
    f32x4 accO[4];
#pragma unroll
    for (int r = 0; r < 4; ++r) { m_i[r] = -1e30f; l_i[r] = 0.f; }
#pragma unroll
    for (int f = 0; f < 4; ++f) accO[f] = (f32x4){0.f, 0.f, 0.f, 0.f};

    for (int t0 = 0; t0 < S_LEN; t0 += 64) {
#pragma unroll
        for (int vv = 0; vv < 2; ++vv) {
            int vecid = tid + 256 * vv;
            int r  = vecid >> 3;
            int cv = vecid & 7;
            size_t grow = (size_t)(b * S_LEN + t0 + r) * DM + h * DEPTH + cv * 8;
            *(bf16x8*)&Ks[r * LDK + cv * 8] = *(const bf16x8*)(Kp + grow);
            bf16x8 vvv = *(const bf16x8*)(Vp + grow);
#pragma unroll
            for (int j = 0; j < 8; ++j)
                Vtl[(cv * 8 + j) * LDK + r] = ((const unsigned short*)&vvv)[j];
        }
        __syncthreads();

        f32x4 sc4[4];
#pragma unroll
        for (int nt = 0; nt < 4; ++nt) {
            f32x4 a = (f32x4){0.f, 0.f, 0.f, 0.f};
            bf16x8 kf0 = *(const bf16x8*)&Ks[(nt * 16 + l16) * LDK + quad * 8];
            bf16x8 kf1 = *(const bf16x8*)&Ks[(nt * 16 + l16) * LDK + 32 + quad * 8];
            a = __builtin_amdgcn_mfma_f32_16x16x32_bf16(qf[0], kf0, a, 0, 0, 0);
            a = __builtin_amdgcn_mfma_f32_16x16x32_bf16(qf[1], kf1, a, 0, 0, 0);
            sc4[nt] = a;
        }
#pragma unroll
        for (int nt = 0; nt < 4; ++nt)
#pragma unroll
            for (int r = 0; r < 4; ++r) sc4[nt][r] *= 0.125f;

#pragma unroll
        for (int r = 0; r < 4; ++r) {
            float mx = fmaxf(fmaxf(sc4[0][r], sc4[1][r]), fmaxf(sc4[2][r], sc4[3][r]));
#pragma unroll
            for (int off = 1; off < 16; off <<= 1)
                mx = fmaxf(mx, __shfl_xor(mx, off, 64));
            float mnew = fmaxf(m_i[r], mx);
            float alpha = __expf(m_i[r] - mnew);
            float rs = 0.f;
#pragma unroll
            for (int nt = 0; nt < 4; ++nt) {
                float p = __expf(sc4[nt][r] - mnew);
                sc4[nt][r] = p;
                rs += p;
            }
#pragma unroll
            for (int off = 1; off < 16; off <<= 1)
                rs += __shfl_xor(rs, off, 64);
            l_i[r] = l_i[r] * alpha + rs;
            m_i[r] = mnew;
#pragma unroll
            for (int f = 0; f < 4; ++f) accO[f][r] *= alpha;
        }

#pragma unroll
        for (int nt = 0; nt < 4; ++nt)
#pragma unroll
            for (int r = 0; r < 4; ++r)
                Ps[wbase + (quad * 4 + r) * LDK + nt * 16 + l16] = f2bf(sc4[nt][r]);
        __syncthreads();

        bf16x8 pf0 = *(const bf16x8*)&Ps[wbase + l16 * LDK + quad * 8];
        bf16x8 pf1 = *(const bf16x8*)&Ps[wbase + l16 * LDK + 32 + quad * 8];
#pragma unroll
        for (int f = 0; f < 4; ++f) {
            bf16x8 vf0 = *(const bf16x8*)&Vtl[(f * 16 + l16) * LDK + quad * 8];
            bf16x8 vf1 = *(const bf16x8*)&Vtl[(f * 16 + l16) * LDK + 32 + quad * 8];
            accO[f] = __builtin_amdgcn_mfma_f32_16x16x32_bf16(pf0, vf0, accO[f], 0, 0, 0);
            accO[f] = __builtin_amdgcn_mfma_f32_16x16x32_bf16(pf1, vf1, accO[f], 0, 0, 0);
        }
        __syncthreads();
    }

#pragma unroll
    for (int f = 0; f < 4; ++f)
#pragma unroll
        for (int r = 0; r < 4; ++r) {
            size_t row = (size_t)b * S_LEN + q0 + wave * 16 + quad * 4 + r;
            out[row * DM + h * DEPTH + f * 16 + l16] = accO[f][r] / l_i[r];
        }
}

// ---------------------------------------------------------------------------
extern "C" void kernel_launch(void* const* d_in, const int* in_sizes, int n_in,
                              void* d_out, int out_size, void* d_ws, size_t ws_size,
                              hipStream_t stream) {
    const float* q  = (const float*)d_in[0];
    const float* k  = (const float*)d_in[1];
    const float* v  = (const float*)d_in[2];
    const float* wq = (const float*)d_in[3];
    const float* wk = (const float*)d_in[4];
    const float* wv = (const float*)d_in[5];
    float* out = (float*)d_out;

    unsigned short* ws = (unsigned short*)d_ws;
    const size_t NPROJ = (size_t)M_ROWS * DM;   // 4,194,304
    const size_t NW    = (size_t)DM * DM;       // 1,048,576

    // fast path ws layout (ushort elements):
    //   region A [0, 3*NPROJ):       Xbf (q,k,v) during proj; then
    //                                Op1(fp32) at [NPROJ,3*NPROJ)
    //   region B [3NP, 3NP+3NW):     Wbf during proj; then lp (fp32, 512 KB)
    //   region C [3NP+3NW, +3NPROJ): Qp, Kp, Vt (Vt written by fused proj)
    const size_t need = (3 * NPROJ + 3 * NW + 3 * NPROJ) * sizeof(unsigned short);

    if (ws_size >= need) {
        unsigned short* Xbf = ws;
        unsigned short* Wbf = ws + 3 * NPROJ;
        unsigned short* Cp  = ws + 3 * NPROJ + 3 * NW;
        unsigned short* Qp  = Cp;
        unsigned short* Kp  = Cp + NPROJ;
        unsigned short* Vt  = Cp + 2 * NPROJ;        // old Vp slot, Vt layout
        float*          Op1 = (float*)(ws + NPROJ);  // overlays Xbf(k,v)
        float*          lp  = (float*)(ws + 3 * NPROJ);  // overlays Wbf

        convert_kernel<<<dim3(256, 6), 256, 0, stream>>>(q, k, v, wq, wk, wv, Xbf);
        proj_gemm3_kernel<<<dim3(M_ROWS / 128, DM / 128, 3), 256, 0, stream>>>(
            Xbf, Wbf, Cp, Vt);
        attn8_kernel<<<dim3(S_LEN / 128, NH, 4), 256, 0, stream>>>(
            Qp, Kp, Vt, out, Op1, lp);
        combine_kernel<<<dim3(M_ROWS * DM / 4 / 256), 256, 0, stream>>>(out, Op1, lp);
    } else {
        unsigned short* Qp = ws;
        unsigned short* Kp = ws + NPROJ;
        unsigned short* Vp = ws + 2 * NPROJ;
        proj_gemm_kernel<<<dim3(M_ROWS / 128, DM / 128, 3), 256, 0, stream>>>(
            q, k, v, wq, wk, wv, Qp, Kp, Vp);
        attn_kernel<<<dim3(S_LEN / 64, NH, B_SZ), 256, 0, stream>>>(Qp, Kp, Vp, out);
    }
}

// Round 14
// 182.807 us; speedup vs baseline: 1.0957x; 1.0201x over previous
//
#include <hip/hip_runtime.h>
#include <hip/hip_bf16.h>
#include <stdint.h>

// Sizes (fixed by the problem)
#define B_SZ 2
#define S_LEN 2048
#define DM 1024
#define NH 16
#define DEPTH 64
#define M_ROWS (B_SZ * S_LEN)   // 4096
#define SCALE_Q 0.1803368801111144f   // log2(e)/sqrt(DEPTH), folded into Q proj

typedef __attribute__((ext_vector_type(8))) short bf16x8;    // 8 bf16 = 4 VGPRs
typedef __attribute__((ext_vector_type(4))) float f32x4;     // 16x16 C/D frag
typedef __attribute__((ext_vector_type(16))) float f32x16;   // 32x32 C/D frag

__device__ __forceinline__ unsigned short f2bf(float x) {
    union { float f; unsigned u; } a; a.f = x;
    unsigned r = a.u + 0x7FFF + ((a.u >> 16) & 1);   // RTNE
    return (unsigned short)(r >> 16);
}

__device__ __forceinline__ bf16x8 u4_to_bf8(uint4 u) {
    union { uint4 a; bf16x8 b; } c; c.a = u; return c.b;   // value bitcast
}

// v_cvt_pk_bf16_f32: D.lo = bf16(lo), D.hi = bf16(hi)  (RTNE).
__device__ __forceinline__ unsigned cvtpk_bf16(float lo, float hi) {
    unsigned r;
    asm("v_cvt_pk_bf16_f32 %0, %1, %2" : "=v"(r) : "v"(lo), "v"(hi));
    return r;
}

// v_permlane32_swap_b32
__device__ __forceinline__ void permswap32(unsigned &a, unsigned &b) {
    auto r = __builtin_amdgcn_permlane32_swap(a, b, false, false);
    a = r[0]; b = r[1];
}

// async global->LDS, 16B per lane. LDS dest = wave-uniform base + lane*16.
__device__ __forceinline__ void async_ld16(const unsigned short* g, void* l) {
    __builtin_amdgcn_global_load_lds(
        (const __attribute__((address_space(1))) void*)g,
        (__attribute__((address_space(3))) void*)l,
        16, 0, 0);
}

// ===========================================================================
// FAST PATH
// ===========================================================================

// ---------------------------------------------------------------------------
// Kernel 1: fp32 -> bf16 convert (RTNE) of q,k,v,wq,wk,wv into ws.
// ---------------------------------------------------------------------------
__global__ __launch_bounds__(256)
void convert_kernel(const float* __restrict__ q, const float* __restrict__ k,
                    const float* __restrict__ v, const float* __restrict__ wq,
                    const float* __restrict__ wk, const float* __restrict__ wv,
                    unsigned short* __restrict__ dst) {
    const int z = blockIdx.y;
    const float* src = (z == 0) ? q : (z == 1) ? k : (z == 2) ? v
                     : (z == 3) ? wq : (z == 4) ? wk : wv;
    const size_t n4  = (z < 3) ? ((size_t)M_ROWS * DM / 4) : ((size_t)DM * DM / 4);
    const size_t off = (z < 3) ? ((size_t)z * M_ROWS * DM)
                               : ((size_t)3 * M_ROWS * DM + (size_t)(z - 3) * DM * DM);
    unsigned short* d = dst + off;
    const size_t stride = (size_t)gridDim.x * blockDim.x;
    for (size_t i = (size_t)blockIdx.x * blockDim.x + threadIdx.x; i < n4; i += stride) {
        float4 x = ((const float4*)src)[i];
        ushort4 p;
        p.x = f2bf(x.x); p.y = f2bf(x.y); p.z = f2bf(x.z); p.w = f2bf(x.w);
        ((ushort4*)d)[i] = p;
    }
}

// ---------------------------------------------------------------------------
// Kernel 2 (R18, unchanged): bf16 NT GEMM, 128x128, BK=64, double-buffered
// global_load_lds, XOR-swizzled LDS, fused V-transpose epilogue.
// ---------------------------------------------------------------------------
__global__ __launch_bounds__(256)
void proj_gemm3_kernel(const unsigned short* __restrict__ Xall,
                       const unsigned short* __restrict__ Wall,
                       unsigned short* __restrict__ Call,
                       unsigned short* __restrict__ Vtp) {
    __shared__ unsigned short SMEM[4 * 128 * 64];   // 64 KB

    const int z = blockIdx.z;
    const unsigned short* X = Xall + (size_t)z * M_ROWS * DM;
    const unsigned short* W = Wall + (size_t)z * DM * DM;
    unsigned short* C = Call + (size_t)z * M_ROWS * DM;

    const int tid  = threadIdx.x;
    const int wave = tid >> 6;
    const int lane = tid & 63;
    const int l32  = lane & 31;
    const int s    = lane >> 5;
    const int m0 = blockIdx.x * 128;
    const int n0 = blockIdx.y * 128;
    const int wm = (wave >> 1) * 64;
    const int wn = (wave & 1) * 64;

    const int r8 = lane >> 3;
    const int sc = (lane & 7) ^ r8;

    f32x16 acc[2][2];
#pragma unroll
    for (int mi = 0; mi < 2; ++mi)
#pragma unroll
        for (int ni = 0; ni < 2; ++ni)
#pragma unroll
            for (int r = 0; r < 16; ++r) acc[mi][ni][r] = 0.f;

    // prologue: stage K-tile 0 into buffer 0
#pragma unroll
    for (int i = 0; i < 4; ++i) {
        const int r = i * 32 + wave * 8 + r8;
        async_ld16(X + (size_t)(m0 + r) * DM + sc * 8,
                   (char*)SMEM + i * 4096 + wave * 1024);
        async_ld16(W + (size_t)(n0 + r) * DM + sc * 8,
                   (char*)SMEM + 32768 + i * 4096 + wave * 1024);
    }

    for (int kk = 0; kk < 16; ++kk) {
        const int cb = kk & 1;

        asm volatile("s_waitcnt vmcnt(0) lgkmcnt(0)" ::: "memory");
        __syncthreads();

        if (kk < 15) {
            const int k0 = (kk + 1) * 64;
            char* ad = (char*)SMEM + (cb ^ 1) * 16384;
            char* bd = (char*)SMEM + 32768 + (cb ^ 1) * 16384;
#pragma unroll
            for (int i = 0; i < 4; ++i) {
                const int r = i * 32 + wave * 8 + r8;
                async_ld16(X + (size_t)(m0 + r) * DM + k0 + sc * 8,
                           ad + i * 4096 + wave * 1024);
                async_ld16(W + (size_t)(n0 + r) * DM + k0 + sc * 8,
                           bd + i * 4096 + wave * 1024);
            }
        }

        const unsigned short* As = SMEM + cb * 8192;
        const unsigned short* Bs = SMEM + 16384 + cb * 8192;

#pragma unroll
        for (int ch = 0; ch < 4; ++ch) {
            bf16x8 af[2], bfr[2];
#pragma unroll
            for (int mi = 0; mi < 2; ++mi) {
                const int row = wm + mi * 32 + l32;
                af[mi] = *(const bf16x8*)&As[row * 64 + (((2 * ch + s) ^ (row & 7)) * 8)];
            }
#pragma unroll
            for (int ni = 0; ni < 2; ++ni) {
                const int row = wn + ni * 32 + l32;
                bfr[ni] = *(const bf16x8*)&Bs[row * 64 + (((2 * ch + s) ^ (row & 7)) * 8)];
            }
#pragma unroll
            for (int mi = 0; mi < 2; ++mi)
#pragma unroll
                for (int ni = 0; ni < 2; ++ni)
                    acc[mi][ni] = __builtin_amdgcn_mfma_f32_32x32x16_bf16(
                        af[mi], bfr[ni], acc[mi][ni], 0, 0, 0);
        }
    }

    if (z < 2) {
        const float scale = (z == 0) ? SCALE_Q : 1.0f;
#pragma unroll
        for (int mi = 0; mi < 2; ++mi)
#pragma unroll
            for (int ni = 0; ni < 2; ++ni)
#pragma unroll
                for (int r = 0; r < 16; ++r) {
                    const int row = m0 + wm + mi * 32 + (r & 3) + 8 * (r >> 2) + 4 * s;
                    const int col = n0 + wn + ni * 32 + l32;
                    C[(size_t)row * DM + col] = f2bf(acc[mi][ni][r] * scale);
                }
    } else {
        // fused V-transpose write (scratch in dead buf0 regions)
        const int b2  = m0 >> 11;
        const int h2  = (n0 + wn) >> 6;
        const int t0l = (m0 & 2047) + wm;
        unsigned short* Tr = SMEM + (wave >> 1) * 16384 + (wave & 1) * 2368;
        const int d_sub = lane >> 3;
        const int tc    = lane & 7;
        unsigned short* VtH =
            Vtp + (size_t)((b2 * NH + h2) * DEPTH) * S_LEN;
#pragma unroll
        for (int ni = 0; ni < 2; ++ni) {
#pragma unroll
            for (int mi = 0; mi < 2; ++mi)
#pragma unroll
                for (int r = 0; r < 16; ++r) {
                    const int tl = mi * 32 + (r & 3) + 8 * (r >> 2) + 4 * s;
                    Tr[tl * 37 + l32] = f2bf(acc[mi][ni][r]);
                }
            asm volatile("s_waitcnt lgkmcnt(0)" ::: "memory");
            __builtin_amdgcn_sched_barrier(0);
#pragma unroll
            for (int di = 0; di < 4; ++di) {
                const int dl = d_sub + di * 8;
                unsigned short tmp[8];
#pragma unroll
                for (int j = 0; j < 8; ++j)
                    tmp[j] = Tr[(tc * 8 + j) * 37 + dl];
                *(bf16x8*)&VtH[(size_t)(ni * 32 + dl) * S_LEN + t0l + tc * 8] =
                    *(const bf16x8*)tmp;
            }
            asm volatile("s_waitcnt lgkmcnt(0)" ::: "memory");
            __builtin_amdgcn_sched_barrier(0);
        }
    }
}

// ---------------------------------------------------------------------------
// Kernel 4 (R19): attention with IN-BLOCK key-split.  4 waves x 32 q rows,
// but waves pair up: pair 0 (w0,w1) processes keys 0-1023, pair 1 (w2,w3)
// keys 1024-2047, over the SAME 64 q rows.  Joint 64-row LDS tiles (rows
// 0-31 = pair-0 keys, 32-63 = pair-1 keys), identical swizzle/staging/drain
// discipline as R18.  Epilogue: pair 1 publishes unnormalized O/l via LDS,
// pair 0 adds (same order as old combine), normalizes, stores out ONCE.
// Deletes the combine kernel, Op1 (33.6 MB), lp, and the double out-write.
// Per-q arithmetic identical -> same absmax.  XCD swizzle kept.
// ---------------------------------------------------------------------------
__global__ __launch_bounds__(256, 4)
void attn8_kernel(const unsigned short* __restrict__ Qp,
                  const unsigned short* __restrict__ Kp,
                  const unsigned short* __restrict__ Vt,
                  float* __restrict__ out) {
    __shared__ __align__(16) char smem[32768];
    unsigned short* Ks = (unsigned short*)smem;              // [2][64*64] 16 KB
    unsigned short* Vs = (unsigned short*)(smem + 16384);    // [2][64*64] 16 KB

    const int tid  = threadIdx.x;
    const int w    = tid >> 6;          // 0..3
    const int p    = w >> 1;            // key-pair (0: keys 0-1023, 1: 1024-2047)
    const int lane = tid & 63;
    const int l32  = lane & 31;
    const int s    = lane >> 5;
    const int r8   = lane >> 3;
    const int sc   = (lane & 7) ^ r8;

    // XCD-aware swizzle: nwg = 32*16*2 = 1024 = 8 XCDs x 128.
    const int lin = blockIdx.x + (blockIdx.y << 5) + (blockIdx.z << 9);
    const int v   = ((lin & 7) << 7) + (lin >> 3);   // bijective
    const int qt  = v & 31;
    const int h   = (v >> 5) & 15;
    const int b   = v >> 9;

    const int q0 = qt * 64 + (w & 1) * 32;   // 32 q rows per wave

    const unsigned short* Kg = Kp + (size_t)(b * S_LEN) * DM + h * DEPTH;
    const unsigned short* Vg = Vt + (size_t)((b * NH + h) * DEPTH) * S_LEN;

    // Q B-frags (prescaled by log2(e)/8 in proj)
    bf16x8 qf[4];
    {
        const unsigned short* pq =
            Qp + (size_t)(b * S_LEN + q0 + l32) * DM + h * DEPTH;
#pragma unroll
        for (int ch = 0; ch < 4; ++ch)
            qf[ch] = *(const bf16x8*)(pq + ch * 16 + s * 8);
    }

    f32x16 oacc[2];   // [db]
    float lacc = 0.f;
#pragma unroll
    for (int db = 0; db < 2; ++db)
#pragma unroll
        for (int r = 0; r < 16; ++r) oacc[db][r] = 0.f;

    // staging helpers: joint tiles, wave w stages K rows [w*16,+16) (its own
    // pair's keys) and V d-rows [w*16,+16) (both pairs' key-chunks, source
    // chunk cc<4 -> pair0 keys, cc>=4 -> pair1 keys).
    // prologue: tile 0 into buffer 0
#pragma unroll
    for (int i = 0; i < 2; ++i) {
        async_ld16(Kg + (size_t)(p * 1024 + (w & 1) * 16 + i * 8 + r8) * DM + sc * 8,
                   (char*)smem + w * 2048 + i * 1024);
        const int cc = sc;
        const int keyoff = (cc >> 2) * 1024 + (cc & 3) * 8;
        async_ld16(Vg + (size_t)(w * 16 + i * 8 + r8) * S_LEN + keyoff,
                   (char*)smem + 16384 + w * 2048 + i * 1024);
    }

    for (int it = 0; it < 32; ++it) {
        const int cb = it & 1;

        // EXPLICIT per-wave drain before the barrier (R11-proven discipline)
        asm volatile("s_waitcnt vmcnt(0) lgkmcnt(0)" ::: "memory");
        __syncthreads();

        // prefetch next 32-key-per-pair joint tiles into cb^1
        if (it < 31) {
            const int tn = (it + 1) * 32;
            char* kd = (char*)smem + (cb ^ 1) * 8192 + w * 2048;
            char* vd = (char*)smem + 16384 + (cb ^ 1) * 8192 + w * 2048;
#pragma unroll
            for (int i = 0; i < 2; ++i) {
                async_ld16(Kg + (size_t)(p * 1024 + tn + (w & 1) * 16 + i * 8 + r8) * DM + sc * 8,
                           kd + i * 1024);
                const int cc = sc;
                const int keyoff = (cc >> 2) * 1024 + tn + (cc & 3) * 8;
                async_ld16(Vg + (size_t)(w * 16 + i * 8 + r8) * S_LEN + keyoff,
                           vd + i * 1024);
            }
        }

        const unsigned short* Kb = Ks + cb * 4096;
        const unsigned short* Vb = Vs + cb * 4096;

        // ---- QK^T: 32 t (own pair) x 32 q ----
        f32x16 sv;
#pragma unroll
        for (int r = 0; r < 16; ++r) sv[r] = 0.f;
        __builtin_amdgcn_s_setprio(1);
#pragma unroll
        for (int ch = 0; ch < 4; ++ch) {
            bf16x8 kf = *(const bf16x8*)
                &Kb[(p * 32 + l32) * 64 + (((2 * ch + s) ^ (l32 & 7)) * 8)];
            sv = __builtin_amdgcn_mfma_f32_32x32x16_bf16(kf, qf[ch], sv, 0, 0, 0);
        }
        __builtin_amdgcn_s_setprio(0);

        // ---- softmax + pack ----
        float pr[16];
#pragma unroll
        for (int r = 0; r < 16; ++r)
            pr[r] = __builtin_amdgcn_exp2f(sv[r]);
        lacc += ((pr[0] + pr[1]) + (pr[2] + pr[3]))
              + ((pr[4] + pr[5]) + (pr[6] + pr[7]))
              + ((pr[8] + pr[9]) + (pr[10] + pr[11]))
              + ((pr[12] + pr[13]) + (pr[14] + pr[15]));
        unsigned a0 = cvtpk_bf16(pr[0],  pr[1]);
        unsigned b0 = cvtpk_bf16(pr[4],  pr[5]);
        unsigned a1 = cvtpk_bf16(pr[2],  pr[3]);
        unsigned b1 = cvtpk_bf16(pr[6],  pr[7]);
        unsigned a2 = cvtpk_bf16(pr[8],  pr[9]);
        unsigned b2 = cvtpk_bf16(pr[12], pr[13]);
        unsigned a3 = cvtpk_bf16(pr[10], pr[11]);
        unsigned b3 = cvtpk_bf16(pr[14], pr[15]);
        permswap32(a0, b0);
        permswap32(a1, b1);
        permswap32(a2, b2);
        permswap32(a3, b3);
        unsigned pw[8];
        pw[0] = a0; pw[1] = a1; pw[2] = b0; pw[3] = b1;
        pw[4] = a2; pw[5] = a3; pw[6] = b2; pw[7] = b3;

        // ---- PV: O^T += V^T P^T (own pair's key slots = p*4 + 2ch + s) ----
#pragma unroll
        for (int ch = 0; ch < 2; ++ch) {
            uint4 pu;
            pu.x = pw[ch * 4 + 0];
            pu.y = pw[ch * 4 + 1];
            pu.z = pw[ch * 4 + 2];
            pu.w = pw[ch * 4 + 3];
            bf16x8 pf = u4_to_bf8(pu);
            __builtin_amdgcn_s_setprio(1);
#pragma unroll
            for (int db = 0; db < 2; ++db) {
                const int drow = db * 32 + l32;
                bf16x8 vf = *(const bf16x8*)
                    &Vb[drow * 64 + (((p * 4 + 2 * ch + s) ^ (l32 & 7)) * 8)];
                oacc[db] = __builtin_amdgcn_mfma_f32_32x32x16_bf16(
                    vf, pf, oacc[db], 0, 0, 0);
            }
            __builtin_amdgcn_s_setprio(0);
        }
    }

    // no direct-to-LDS write may outlive the main loop; all reads done
    asm volatile("s_waitcnt vmcnt(0)" ::: "memory");
    __syncthreads();

    // ---- pair exchange: pair 1 publishes O/l, pair 0 adds ----
    // LDS floats: Ex oacc [0,4096) (w2 -> [0,2048), w3 -> [2048,4096)),
    // lacc [4096,4224), Linv [4224,4288); Of scratch at byte 18432+.
    float* Ex = (float*)smem;
    if (w >= 2) {
        float* dst = Ex + (w - 2) * 2048;
#pragma unroll
        for (int db = 0; db < 2; ++db)
#pragma unroll
            for (int r = 0; r < 16; ++r)
                dst[(db * 16 + r) * 64 + lane] = oacc[db][r];
        Ex[4096 + (w - 2) * 64 + lane] = lacc;
    }
    asm volatile("s_waitcnt lgkmcnt(0)" ::: "memory");
    __syncthreads();

    if (w < 2) {
        float* src = Ex + w * 2048;
#pragma unroll
        for (int db = 0; db < 2; ++db)
#pragma unroll
            for (int r = 0; r < 16; ++r)
                oacc[db][r] += src[(db * 16 + r) * 64 + lane];
        lacc += Ex[4096 + w * 64 + lane];
        const float lt = lacc + __shfl_xor(lacc, 32, 64);
        const float inv = 1.0f / lt;
        if (s == 0) Ex[4224 + w * 32 + l32] = inv;
        asm volatile("s_waitcnt lgkmcnt(0)" ::: "memory");
        __builtin_amdgcn_sched_barrier(0);

        // epilogue: O^T -> LDS transpose (2 chunks of 16 q) -> normalized
        // stores.  Per-wave scratch; intra-wave ds ordering via fences.
        float* Of = (float*)(smem + 18432 + w * 4608);
#pragma unroll
        for (int c = 0; c < 2; ++c) {
            if ((l32 >> 4) == c) {
                const int qh = l32 & 15;
#pragma unroll
                for (int db = 0; db < 2; ++db)
#pragma unroll
                    for (int m = 0; m < 4; ++m) {
                        float4 v4;
                        v4.x = oacc[db][4 * m + 0];
                        v4.y = oacc[db][4 * m + 1];
                        v4.z = oacc[db][4 * m + 2];
                        v4.w = oacc[db][4 * m + 3];
                        *(float4*)&Of[qh * 68 + db * 32 + 8 * m + 4 * s] = v4;
                    }
            }
            asm volatile("s_waitcnt lgkmcnt(0)" ::: "memory");
            __builtin_amdgcn_sched_barrier(0);
#pragma unroll
            for (int i = 0; i < 4; ++i) {
                const int row = i * 4 + (lane >> 4);
                const int c4 = lane & 15;
                float4 v4 = *(const float4*)&Of[row * 68 + c4 * 4];
                const float iv = Ex[4224 + w * 32 + c * 16 + row];
                v4.x *= iv; v4.y *= iv; v4.z *= iv; v4.w *= iv;
                *(float4*)&out[(size_t)(b * S_LEN + q0 - (w & 1) * 32
                                        + (w & 1) * 32 + c * 16 + row) * DM
                               + h * DEPTH + c4 * 4] = v4;
            }
            asm volatile("s_waitcnt lgkmcnt(0)" ::: "memory");
            __builtin_amdgcn_sched_barrier(0);
        }
    }
}

// ===========================================================================
// FALLBACK PATH (round-1 proven kernels, used only if ws is too small)
// ===========================================================================
#define LDK 72

__global__ __launch_bounds__(256)
void proj_gemm_kernel(const float* __restrict__ q, const float* __restrict__ k,
                      const float* __restrict__ v, const float* __restrict__ wq,
                      const float* __restrict__ wk, const float* __restrict__ wv,
                      unsigned short* __restrict__ Qp, unsigned short* __restrict__ Kp,
                      unsigned short* __restrict__ Vp) {
    __shared__ unsigned short As[128 * LDK];
    __shared__ unsigned short Bs[128 * LDK];

    const int z = blockIdx.z;
    const float* __restrict__ X = (z == 0) ? q : (z == 1) ? k : v;
    const float* __restrict__ W = (z == 0) ? wq : (z == 1) ? wk : wv;
    unsigned short* __restrict__ C = (z == 0) ? Qp : (z == 1) ? Kp : Vp;

    const int tid  = threadIdx.x;
    const int wave = tid >> 6;
    const int lane = tid & 63;
    const int quad = lane >> 4;
    const int l16  = lane & 15;
    const int m0 = blockIdx.x * 128;
    const int n0 = blockIdx.y * 128;
    const int wm = (wave >> 1) * 64;
    const int wn = (wave & 1) * 64;

    f32x4 acc[4][4];
#pragma unroll
    for (int mt = 0; mt < 4; ++mt)
#pragma unroll
        for (int nt = 0; nt < 4; ++nt)
            acc[mt][nt] = (f32x4){0.f, 0.f, 0.f, 0.f};

    for (int k0 = 0; k0 < DM; k0 += 64) {
#pragma unroll
        for (int vv = 0; vv < 8; ++vv) {
            int vecid = tid + 256 * vv;
            int r  = vecid >> 4;
            int c4 = vecid & 15;
            const float4 xa = *(const float4*)&X[(size_t)(m0 + r) * DM + k0 + c4 * 4];
            ushort4 pa;
            pa.x = f2bf(xa.x); pa.y = f2bf(xa.y); pa.z = f2bf(xa.z); pa.w = f2bf(xa.w);
            *(ushort4*)&As[r * LDK + c4 * 4] = pa;
            const float4 xb = *(const float4*)&W[(size_t)(n0 + r) * DM + k0 + c4 * 4];
            ushort4 pb;
            pb.x = f2bf(xb.x); pb.y = f2bf(xb.y); pb.z = f2bf(xb.z); pb.w = f2bf(xb.w);
            *(ushort4*)&Bs[r * LDK + c4 * 4] = pb;
        }
        __syncthreads();

#pragma unroll
        for (int kc = 0; kc < 2; ++kc) {
            bf16x8 af[4], bfr[4];
#pragma unroll
            for (int mt = 0; mt < 4; ++mt)
                af[mt] = *(const bf16x8*)&As[(wm + mt * 16 + l16) * LDK + kc * 32 + quad * 8];
#pragma unroll
            for (int nt = 0; nt < 4; ++nt)
                bfr[nt] = *(const bf16x8*)&Bs[(wn + nt * 16 + l16) * LDK + kc * 32 + quad * 8];
#pragma unroll
            for (int mt = 0; mt < 4; ++mt)
#pragma unroll
                for (int nt = 0; nt < 4; ++nt)
                    acc[mt][nt] = __builtin_amdgcn_mfma_f32_16x16x32_bf16(
                        af[mt], bfr[nt], acc[mt][nt], 0, 0, 0);
        }
        __syncthreads();
    }

#pragma unroll
    for (int mt = 0; mt < 4; ++mt)
#pragma unroll
        for (int nt = 0; nt < 4; ++nt)
#pragma unroll
            for (int r = 0; r < 4; ++r) {
                int row = m0 + wm + mt * 16 + quad * 4 + r;
                int col = n0 + wn + nt * 16 + l16;
                C[(size_t)row * DM + col] = f2bf(acc[mt][nt][r]);
            }
}

__global__ __launch_bounds__(256)
void attn_kernel(const unsigned short* __restrict__ Qp,
                 const unsigned short* __restrict__ Kp,
                 const unsigned short* __restrict__ Vp,
                 float* __restrict__ out) {
    __shared__ unsigned short Ks[64 * LDK];
    __shared__ unsigned short Vtl[64 * LDK];
    __shared__ unsigned short Ps[4 * 16 * LDK];

    const int tid  = threadIdx.x;
    const int wave = tid >> 6;
    const int lane = tid & 63;
    const int quad = lane >> 4;
    const int l16  = lane & 15;
    const int q0 = blockIdx.x * 64;
    const int h  = blockIdx.y;
    const int b  = blockIdx.z;
    const int wbase = wave * 16 * LDK;

    bf16x8 qf[2];
    {
        size_t row = (size_t)b * S_LEN + q0 + wave * 16 + l16;
        const unsigned short* p = Qp + row * DM + h * DEPTH;
        qf[0] = *(const bf16x8*)(p + quad * 8);
        qf[1] = *(const bf16x8*)(p + 32 + quad * 8);
    }

    float m_i[4], l_i[4];
    f32x4 accO[4];
#pragma unroll
    for (int r = 0; r < 4; ++r) { m_i[r] = -1e30f; l_i[r] = 0.f; }
#pragma unroll
    for (int f = 0; f < 4; ++f) accO[f] = (f32x4){0.f, 0.f, 0.f, 0.f};

    for (int t0 = 0; t0 < S_LEN; t0 += 64) {
#pragma unroll
        for (int vv = 0; vv < 2; ++vv) {
            int vecid = tid + 256 * vv;
            int r  = vecid >> 3;
            int cv = vecid & 7;
            size_t grow = (size_t)(b * S_LEN + t0 + r) * DM + h * DEPTH + cv * 8;
            *(bf16x8*)&Ks[r * LDK + cv * 8] = *(const bf16x8*)(Kp + grow);
            bf16x8 vvv = *(const bf16x8*)(Vp + grow);
#pragma unroll
            for (int j = 0; j < 8; ++j)
                Vtl[(cv * 8 + j) * LDK + r] = ((const unsigned short*)&vvv)[j];
        }
        __syncthreads();

        f32x4 sc4[4];
#pragma unroll
        for (int nt = 0; nt < 4; ++nt) {
            f32x4 a = (f32x4){0.f, 0.f, 0.f, 0.f};
            bf16x8 kf0 = *(const bf16x8*)&Ks[(nt * 16 + l16) * LDK + quad * 8];
            bf16x8 kf1 = *(const bf16x8*)&Ks[(nt * 16 + l16) * LDK + 32 + quad * 8];
            a = __builtin_amdgcn_mfma_f32_16x16x32_bf16(qf[0], kf0, a, 0, 0, 0);
            a = __builtin_amdgcn_mfma_f32_16x16x32_bf16(qf[1], kf1, a, 0, 0, 0);
            sc4[nt] = a;
        }
#pragma unroll
        for (int nt = 0; nt < 4; ++nt)
#pragma unroll
            for (int r = 0; r < 4; ++r) sc4[nt][r] *= 0.125f;

#pragma unroll
        for (int r = 0; r < 4; ++r) {
            float mx = fmaxf(fmaxf(sc4[0][r], sc4[1][r]), fmaxf(sc4[2][r], sc4[3][r]));
#pragma unroll
            for (int off = 1; off < 16; off <<= 1)
                mx = fmaxf(mx, __shfl_xor(mx, off, 64));
            float mnew = fmaxf(m_i[r], mx);
            float alpha = __expf(m_i[r] - mnew);
            float rs = 0.f;
#pragma unroll
            for (int nt = 0; nt < 4; ++nt) {
                float p = __expf(sc4[nt][r] - mnew);
                sc4[nt][r] = p;
                rs += p;
            }
#pragma unroll
            for (int off = 1; off < 16; off <<= 1)
                rs += __shfl_xor(rs, off, 64);
            l_i[r] = l_i[r] * alpha + rs;
            m_i[r] = mnew;
#pragma unroll
            for (int f = 0; f < 4; ++f) accO[f][r] *= alpha;
        }

#pragma unroll
        for (int nt = 0; nt < 4; ++nt)
#pragma unroll
            for (int r = 0; r < 4; ++r)
                Ps[wbase + (quad * 4 + r) * LDK + nt * 16 + l16] = f2bf(sc4[nt][r]);
        __syncthreads();

        bf16x8 pf0 = *(const bf16x8*)&Ps[wbase + l16 * LDK + quad * 8];
        bf16x8 pf1 = *(const bf16x8*)&Ps[wbase + l16 * LDK + 32 + quad * 8];
#pragma unroll
        for (int f = 0; f < 4; ++f) {
            bf16x8 vf0 = *(const bf16x8*)&Vtl[(f * 16 + l16) * LDK + quad * 8];
            bf16x8 vf1 = *(const bf16x8*)&Vtl[(f * 16 + l16) * LDK + 32 + quad * 8];
            accO[f] = __builtin_amdgcn_mfma_f32_16x16x32_bf16(pf0, vf0, accO[f], 0, 0, 0);
            accO[f] = __builtin_amdgcn_mfma_f32_16x16x32_bf16(pf1, vf1, accO[f], 0, 0, 0);
        }
        __syncthreads();
    }

#pragma unroll
    for (int f = 0; f < 4; ++f)
#pragma unroll
        for (int r = 0; r < 4; ++r) {
            size_t row = (size_t)b * S_LEN + q0 + wave * 16 + quad * 4 + r;
            out[row * DM + h * DEPTH + f * 16 + l16] = accO[f][r] / l_i[r];
        }
}

// ---------------------------------------------------------------------------
extern "C" void kernel_launch(void* const* d_in, const int* in_sizes, int n_in,
                              void* d_out, int out_size, void* d_ws, size_t ws_size,
                              hipStream_t stream) {
    const float* q  = (const float*)d_in[0];
    const float* k  = (const float*)d_in[1];
    const float* v  = (const float*)d_in[2];
    const float* wq = (const float*)d_in[3];
    const float* wk = (const float*)d_in[4];
    const float* wv = (const float*)d_in[5];
    float* out = (float*)d_out;

    unsigned short* ws = (unsigned short*)d_ws;
    const size_t NPROJ = (size_t)M_ROWS * DM;   // 4,194,304
    const size_t NW    = (size_t)DM * DM;       // 1,048,576

    // fast path ws layout (ushort elements):
    //   region A [0, 3*NPROJ):       Xbf (q,k,v) during proj
    //   region B [3NP, 3NP+3NW):     Wbf during proj
    //   region C [3NP+3NW, +3NPROJ): Qp, Kp, Vt (Vt written by fused proj)
    const size_t need = (3 * NPROJ + 3 * NW + 3 * NPROJ) * sizeof(unsigned short);

    if (ws_size >= need) {
        unsigned short* Xbf = ws;
        unsigned short* Wbf = ws + 3 * NPROJ;
        unsigned short* Cp  = ws + 3 * NPROJ + 3 * NW;
        unsigned short* Qp  = Cp;
        unsigned short* Kp  = Cp + NPROJ;
        unsigned short* Vt  = Cp + 2 * NPROJ;        // Vt layout

        convert_kernel<<<dim3(256, 6), 256, 0, stream>>>(q, k, v, wq, wk, wv, Xbf);
        proj_gemm3_kernel<<<dim3(M_ROWS / 128, DM / 128, 3), 256, 0, stream>>>(
            Xbf, Wbf, Cp, Vt);
        attn8_kernel<<<dim3(S_LEN / 64, NH, B_SZ), 256, 0, stream>>>(
            Qp, Kp, Vt, out);
    } else {
        unsigned short* Qp = ws;
        unsigned short* Kp = ws + NPROJ;
        unsigned short* Vp = ws + 2 * NPROJ;
        proj_gemm_kernel<<<dim3(M_ROWS / 128, DM / 128, 3), 256, 0, stream>>>(
            q, k, v, wq, wk, wv, Qp, Kp, Vp);
        attn_kernel<<<dim3(S_LEN / 64, NH, B_SZ), 256, 0, stream>>>(Qp, Kp, Vp, out);
    }
}